// Round 6
// baseline (708.029 us; speedup 1.0000x reference)
//
#include <hip/hip_runtime.h>
#include <math.h>

#define NB 8
#define NGRID 343
#define HID 64
#define NPATH 20

// ---------------- compile-time Clifford tables (Cl(3,0), blade order:
// 1, e1, e2, e3, e12, e13, e23, e123 — matches reference combinations order) ---
struct Tab {
  int prod_idx[8][8];  // blade index of product blade_k * blade_m
  int prod_sgn[8][8];  // sign of that product
  int pid[4][4][4];    // path id for (grade_left, grade_out, grade_right), 20 = dead
  int grade[8];        // grade of blade idx
  int kk_idx[8][8];    // for (l,m): unique k with prod(k,m) = +-l
  int kk_sgn[8][8];    // C[kk, l, m]
};

constexpr Tab make_tab() {
  Tab t{};
  int mask[8]  = {0,1,2,4,3,5,6,7};  // blade idx -> bitmask
  int idxof[8] = {0,1,2,4,3,5,6,7};  // bitmask -> blade idx
  for (int k = 0; k < 8; ++k) {
    int g = 0;
    for (int b = 0; b < 3; ++b) g += (mask[k] >> b) & 1;
    t.grade[k] = g;
  }
  for (int k = 0; k < 8; ++k)
    for (int m = 0; m < 8; ++m) {
      int A = mask[k], B = mask[m];
      t.prod_idx[k][m] = idxof[A ^ B];
      int c = 0;
      for (int i = 0; i < 3; ++i)
        if ((B >> i) & 1)
          for (int j = i + 1; j < 3; ++j)
            if ((A >> j) & 1) c++;
      t.prod_sgn[k][m] = (c & 1) ? -1 : 1;
    }
  int pc = 0;
  for (int a = 0; a < 4; ++a)
    for (int b = 0; b < 4; ++b)
      for (int c = 0; c < 4; ++c) {
        bool ok = false;
        for (int k = 0; k < 8; ++k)
          for (int m = 0; m < 8; ++m)
            if (t.grade[k] == a && t.grade[m] == c &&
                t.grade[t.prod_idx[k][m]] == b)
              ok = true;
        t.pid[a][b][c] = ok ? pc++ : NPATH;
      }
  for (int l = 0; l < 8; ++l)
    for (int m = 0; m < 8; ++m)
      for (int k = 0; k < 8; ++k)
        if (t.prod_idx[k][m] == l) {
          t.kk_idx[l][m] = k;
          t.kk_sgn[l][m] = t.prod_sgn[k][m];
        }
  return t;
}
constexpr Tab TB = make_tab();

// ---------------- workspace layout (floats) ----------------
// lin0_t [4][33][64]          @ 0        (8448)   ([g][ch][hh])
// lins_t [3][4][64][64]       @ 8448     (49152)  ([l][g][i][hh])
// gps_t  [4][64][20][64]      @ 57600    (327680) ([l][i][p][o])
// outW_t [4][64][1024]        @ 385280   (262144) ([g][i][oc])
// k_ws   [1024][343][8]       @ 647424   (2809856)
// JOURNAL (hard-won, do not regress):
//  - Weight loads must be lane-coalesced (4B/lane x 64 = 256B/inst).
//    v3's per-thread float4 from strided bases = 64-line scatter -> 97->160us.
//  - v4 (1024thr, launch_bounds(1024,4)) got VGPR cap 64 -> prefetch spilled
//    to scratch (FETCH/WRITE 19/31MB) -> 123us. Prefetch NEEDS reg headroom.
//  - v5 (gp weights double-buffered through LDS) -> 105us: __syncthreads()
//    drains vmcnt(0), so "prefetch across barrier" is impossible in HIP;
//    extra barriers cost more than the staging saved.
//  - expand is NOT a ~100us kernel (r5: coalesced rewrite changed total by
//    ~0); total-net ≈ 129us is expand(~20-30)+prep(~5)+harness overhead.
#define OFF_LIN0T 0
#define OFF_LINST 8448
#define OFF_GPST  57600
#define OFF_OUTWT 385280
#define OFF_KWS   647424

// ---------------- kernel 0: weight transpose ----------------
__global__ void ccs_prep_kernel(const float* __restrict__ lin0_W,
                                const float* __restrict__ lins_W,
                                const float* __restrict__ gps_w,
                                const float* __restrict__ out_W,
                                float* __restrict__ ws) {
  const int TOT = 8448 + 49152 + 327680 + 262144;
  for (int d = blockIdx.x * blockDim.x + threadIdx.x; d < TOT;
       d += gridDim.x * blockDim.x) {
    float v;
    if (d < 8448) {
      int idx = d;
      int hh = idx & 63, ch = (idx >> 6) % 33, g = (idx >> 6) / 33;
      v = lin0_W[(g * 64 + hh) * 33 + ch];
    } else if (d < 8448 + 49152) {
      int idx = d - OFF_LINST;
      int hh = idx & 63, i = (idx >> 6) & 63, g = (idx >> 12) & 3, l = idx >> 14;
      v = lins_W[((l * 4 + g) * 64 + hh) * 64 + i];
    } else if (d < 8448 + 49152 + 327680) {
      int idx = d - OFF_GPST;
      int o = idx & 63, p = (idx >> 6) % 20, i = ((idx >> 6) / 20) & 63,
          l = idx / 81920;
      v = gps_w[((l * 64 + o) * 64 + i) * 20 + p];
    } else {
      int idx = d - OFF_OUTWT;
      int oc = idx & 1023, i = (idx >> 10) & 63, g = idx >> 16;
      v = out_W[(g * 1024 + oc) * 64 + i];
    }
    ws[d] = v;
  }
}

// ---------------- kernel 1: per-grid-point network ----------------
// v7 = v2 (97us verified, coalesced scalar weight loads) + register
// software-pipelining: launch_bounds(512,2) opens the VGPR cap to 256
// (grid=172 -> 1 block/CU -> 8 waves/CU regardless), and gp/lin/out
// prefetch the NEXT iteration's weights into registers while computing
// the current one. Addresses are untouched (still lane-coalesced).
__launch_bounds__(512, 2)
__global__ void ccs_net_kernel(const float* __restrict__ condition,
                               const float* __restrict__ rel_pos_sigma,
                               const float* __restrict__ lin0_b,
                               const float* __restrict__ act0_a,
                               const float* __restrict__ act0_b,
                               const float* __restrict__ lins_b,
                               const float* __restrict__ acts_a,
                               const float* __restrict__ acts_b,
                               const float* __restrict__ out_b,
                               const float* __restrict__ shell_sigma,
                               const float* __restrict__ ws,
                               float* __restrict__ kws) {
  const float* lin0t = ws + OFF_LIN0T;
  const float* linst = ws + OFF_LINST;
  const float* gpst  = ws + OFF_GPST;
  const float* outwt = ws + OFF_OUTWT;

  __shared__ float xb[33 * 8];       // condition channels (shared by both pts)
  __shared__ float x0r[2][8];        // per-point geometric row (ch 0)
  __shared__ __align__(16) float F0[2 * 512];
  __shared__ __align__(16) float F1[2 * 512];
  __shared__ float part[2 * 8 * 8 * 64];  // [pt][isub][j][o] stride-1 in o

  const int tid = threadIdx.x;
  const int n0 = blockIdx.x * 2;
  const int n1 = n0 + 1;

  const float sig = rel_pos_sigma[0];

  float qq[2];
  {
    int iz = n0 % 7, iy = (n0 / 7) % 7, ix = n0 / 49;
    float px = (float)ix - 3.f, py = (float)iy - 3.f, pz = (float)iz - 3.f;
    qq[0] = px * px + py * py + pz * pz;
  }
  {
    int nc = (n1 < NGRID) ? n1 : (NGRID - 1);  // clamp: last block's pt1
    int iz = nc % 7, iy = (nc / 7) % 7, ix = nc / 49;
    float px = (float)ix - 3.f, py = (float)iy - 3.f, pz = (float)iz - 3.f;
    qq[1] = px * px + py * py + pz * pz;
  }

  for (int t = tid; t < 264; t += 512) {
    int ch = t >> 3, b = t & 7;
    xb[t] = (ch == 0) ? 0.f : condition[(ch - 1) * 8 + b];
  }
  if (tid < 16) {
    int pt = tid >> 3, b = tid & 7;
    int nc = n0 + pt;
    if (nc >= NGRID) nc = NGRID - 1;
    int iz = nc % 7, iy = (nc / 7) % 7, ix = nc / 49;
    float px = (float)ix - 3.f, py = (float)iy - 3.f, pz = (float)iz - 3.f;
    float q = px * px + py * py + pz * pz;
    float scal = expf(-q / (2.f * sig * sig));
    x0r[pt][b] =
        (b == 0) ? scal : (b == 1) ? px : (b == 2) ? py : (b == 3) ? pz : 0.f;
  }
  __syncthreads();

  const int b8 = tid & 7;
  const int hh = (tid >> 3) & 63;  // 0..63
  const int gb = TB.grade[b8];

  // ---- lin0: x (33 ch) -> F0, both points per thread ----
  {
    const float* wrow = lin0t + gb * 33 * 64 + hh;
    float w0 = wrow[0];
    float a0 = w0 * x0r[0][b8];
    float a1 = w0 * x0r[1][b8];
    if (b8 == 0) {
      float bb = lin0_b[hh];
      a0 += bb;
      a1 += bb;
    }
    #pragma unroll
    for (int ch = 1; ch < 33; ++ch) {
      float w = wrow[ch * 64];
      float xv = xb[ch * 8 + b8];
      a0 = fmaf(w, xv, a0);
      a1 = fmaf(w, xv, a1);
    }
    F0[hh * 8 + b8] = a0;
    F0[512 + hh * 8 + b8] = a1;
  }
  __syncthreads();

  // ---- helpers (src/dst are [2][512] bases; pt stride 512) ----
  auto silu = [&](const float* src, float* dst, const float* aa,
                  const float* bb) {
    int s0 = (gb == 0) ? 0 : (gb == 1) ? 1 : (gb == 2) ? 4 : 7;
    int cnt = (gb == 0 || gb == 3) ? 1 : 3;
    float A = aa[hh * 4 + gb], B = bb[hh * 4 + gb];
    #pragma unroll
    for (int pt = 0; pt < 2; ++pt) {
      float qg = 0.f;
      for (int u = 0; u < cnt; ++u) {
        float v = src[pt * 512 + hh * 8 + s0 + u];
        qg = fmaf(v, v, qg);
      }
      float z = fmaf(A, qg, B);
      float gate = 1.f / (1.f + expf(-z));
      dst[pt * 512 + hh * 8 + b8] = src[pt * 512 + hh * 8 + b8] * gate;
    }
  };

  auto lin = [&](const float* src, float* dst, const float* wt,
                 const float* bias) {
    const float* wrow = wt + gb * 64 * 64 + hh;
    float a0 = 0.f, a1 = 0.f;
    if (b8 == 0) {
      float bb = bias[hh];
      a0 = bb;
      a1 = bb;
    }
    float w = wrow[0];
    #pragma unroll
    for (int i = 0; i < 64; ++i) {
      float wnx;
      if (i < 63) wnx = wrow[(i + 1) * 64];  // 1-ahead prefetch
      a0 = fmaf(w, src[i * 8 + b8], a0);
      a1 = fmaf(w, src[512 + i * 8 + b8], a1);
      if (i < 63) w = wnx;
    }
    dst[hh * 8 + b8] = a0;
    dst[512 + hh * 8 + b8] = a1;
  };

  auto gp = [&](const float* src, float* dst, const float* wl) {
    const int o = tid & 63;
    const int isub = tid >> 6;  // 0..7, 8 i's each
    float fa[8], fb[8];
    #pragma unroll
    for (int j = 0; j < 8; ++j) {
      fa[j] = 0.f;
      fb[j] = 0.f;
    }
    const float* wb0 = wl + (isub * 8) * 1280 + o;  // i-stride 20*64=1280
    float wp[20];
    #pragma unroll
    for (int p = 0; p < 20; ++p) wp[p] = wb0[p * 64];  // lane-coalesced
    #pragma unroll
    for (int it = 0; it < 8; ++it) {
      float wn[20];
      if (it < 7) {  // issue next i's 20 loads; latency hides under compute
        const float* nb = wb0 + (it + 1) * 1280;
        #pragma unroll
        for (int p = 0; p < 20; ++p) wn[p] = nb[p * 64];
      }
      int i = isub * 8 + it;
      float4 va0 = *(const float4*)(src + i * 8);
      float4 va1 = *(const float4*)(src + i * 8 + 4);
      float4 vb0 = *(const float4*)(src + 512 + i * 8);
      float4 vb1 = *(const float4*)(src + 512 + i * 8 + 4);
      float xA[8] = {va0.x, va0.y, va0.z, va0.w, va1.x, va1.y, va1.z, va1.w};
      float xB[8] = {vb0.x, vb0.y, vb0.z, vb0.w, vb1.x, vb1.y, vb1.z, vb1.w};
      #pragma unroll
      for (int k = 0; k < 8; ++k) {
        #pragma unroll
        for (int m = 0; m < 8; ++m) {
          const int j = TB.prod_idx[k][m];
          const int p = TB.pid[TB.grade[k]][TB.grade[j]][TB.grade[m]];
          if (TB.prod_sgn[k][m] > 0) {
            fa[j] = fmaf(xA[k] * xA[m], wp[p], fa[j]);
            fb[j] = fmaf(xB[k] * xB[m], wp[p], fb[j]);
          } else {
            fa[j] = fmaf(-xA[k] * xA[m], wp[p], fa[j]);
            fb[j] = fmaf(-xB[k] * xB[m], wp[p], fb[j]);
          }
        }
      }
      if (it < 7) {
        #pragma unroll
        for (int p = 0; p < 20; ++p) wp[p] = wn[p];
      }
    }
    // part layout [pt][isub][j][o]: stride-1 in o -> conflict-free
    #pragma unroll
    for (int j = 0; j < 8; ++j) {
      part[isub * 512 + j * 64 + o] = fa[j];
      part[4096 + isub * 512 + j * 64 + o] = fb[j];
    }
    __syncthreads();
    #pragma unroll
    for (int r = 0; r < 2; ++r) {
      int item = tid + r * 512;  // 1024 items = 2pt x 64o x 8j
      int oo = item & 63;
      int j = (item >> 6) & 7;
      int pt = item >> 9;
      const float* pp = part + pt * 4096 + j * 64 + oo;
      float s = pp[0] + pp[512] + pp[1024] + pp[1536] + pp[2048] + pp[2560] +
                pp[3072] + pp[3584];
      dst[pt * 512 + oo * 8 + j] = s * 0.125f;
    }
    __syncthreads();
  };

  // ---- layer 0 ----
  silu(F0, F1, act0_a, act0_b);
  __syncthreads();
  gp(F1, F0, gpst + 0);  // features now in F0

  // ---- layers 1..3 ----
  float* f = F0;
  float* g_ = F1;
  for (int l = 0; l < 3; ++l) {
    lin(f, g_, linst + l * 16384, lins_b + l * 64);
    __syncthreads();
    silu(g_, f, acts_a + l * 256, acts_b + l * 256);
    __syncthreads();
    gp(f, g_, gpst + (l + 1) * 81920);  // result in g_
    float* t = f; f = g_; g_ = t;       // features in f
  }

  // ---- output linear + shell (both points per thread) ----
  const float FACTOR = 1.0f / sqrtf(343.0f);
  #pragma unroll
  for (int r = 0; r < 2; ++r) {
    int oc = tid + r * 512;
    float acc[2][8];
    #pragma unroll
    for (int pt = 0; pt < 2; ++pt)
      #pragma unroll
      for (int b = 0; b < 8; ++b) acc[pt][b] = 0.f;
    {
      float bb = out_b[oc];
      acc[0][0] = bb;
      acc[1][0] = bb;
    }
    float w0 = outwt[(0 * 64 + 0) * 1024 + oc];
    float w1 = outwt[(1 * 64 + 0) * 1024 + oc];
    float w2 = outwt[(2 * 64 + 0) * 1024 + oc];
    float w3 = outwt[(3 * 64 + 0) * 1024 + oc];
    #pragma unroll
    for (int i = 0; i < 64; ++i) {
      float wn0, wn1, wn2, wn3;
      if (i < 63) {  // 1-ahead prefetch of the 4 grade rows
        wn0 = outwt[(0 * 64 + i + 1) * 1024 + oc];
        wn1 = outwt[(1 * 64 + i + 1) * 1024 + oc];
        wn2 = outwt[(2 * 64 + i + 1) * 1024 + oc];
        wn3 = outwt[(3 * 64 + i + 1) * 1024 + oc];
      }
      #pragma unroll
      for (int pt = 0; pt < 2; ++pt) {
        float h[8];
        *(float4*)h = *(const float4*)(f + pt * 512 + i * 8);
        *(float4*)(h + 4) = *(const float4*)(f + pt * 512 + i * 8 + 4);
        acc[pt][0] = fmaf(w0, h[0], acc[pt][0]);
        acc[pt][1] = fmaf(w1, h[1], acc[pt][1]);
        acc[pt][2] = fmaf(w1, h[2], acc[pt][2]);
        acc[pt][3] = fmaf(w1, h[3], acc[pt][3]);
        acc[pt][4] = fmaf(w2, h[4], acc[pt][4]);
        acc[pt][5] = fmaf(w2, h[5], acc[pt][5]);
        acc[pt][6] = fmaf(w2, h[6], acc[pt][6]);
        acc[pt][7] = fmaf(w3, h[7], acc[pt][7]);
      }
      if (i < 63) {
        w0 = wn0; w1 = wn1; w2 = wn2; w3 = wn3;
      }
    }
    float sh[8];
    *(float4*)sh = *(const float4*)(shell_sigma + oc * 8);
    *(float4*)(sh + 4) = *(const float4*)(shell_sigma + oc * 8 + 4);
    #pragma unroll
    for (int pt = 0; pt < 2; ++pt) {
      int n = n0 + pt;
      if (n < NGRID) {
        float q = qq[pt];
        float out8[8];
        #pragma unroll
        for (int b = 0; b < 8; ++b)
          out8[b] = acc[pt][b] * expf(-q / (sh[b] * sh[b])) * FACTOR;
        float4* dstp = (float4*)(kws + ((size_t)oc * 343 + n) * 8);
        dstp[0] = make_float4(out8[0], out8[1], out8[2], out8[3]);
        dstp[1] = make_float4(out8[4], out8[5], out8[6], out8[7]);
      }
    }
  }
}

// ---------------- kernel 2: Cayley expansion to output ----------------
// One block (256 thr) per oi. kws[oi] staged transposed in LDS
// (kT[b][n], stride-1 reads), output written as n-contiguous coalesced
// rows (64 rows x 343 floats per block).
__launch_bounds__(256)
__global__ void ccs_expand_kernel(const float* __restrict__ cayley_w,
                                  const float* __restrict__ kws,
                                  float* __restrict__ out) {
  const int oi = blockIdx.x;  // o*32 + i, 0..1023
  const int tid = threadIdx.x;
  __shared__ float kT[8][344];  // [blade][n], padded

  // stage kws[oi][n][b] -> kT[b][n] (coalesced float4 reads)
  const float4* src = (const float4*)(kws + (size_t)oi * 343 * 8);
  for (int t = tid; t < 686; t += 256) {  // 686 float4 = 343*8 floats
    float4 v = src[t];
    int n = t >> 1, b = (t & 1) * 4;
    kT[b][n] = v.x;
    kT[b + 1][n] = v.y;
    kT[b + 2][n] = v.z;
    kT[b + 3][n] = v.w;
  }
  float cw[20];
  #pragma unroll
  for (int p = 0; p < 20; ++p) cw[p] = cayley_w[oi * 20 + p];  // broadcast
  __syncthreads();

  const int o = oi >> 5, i = oi & 31;
  #pragma unroll
  for (int l = 0; l < 8; ++l) {
    #pragma unroll
    for (int m = 0; m < 8; ++m) {
      const int kk = TB.kk_idx[l][m];
      const int p = TB.pid[TB.grade[kk]][TB.grade[l]][TB.grade[m]];
      float c = (TB.kk_sgn[l][m] < 0) ? -cw[p] : cw[p];
      float* dst = out + ((size_t)((o * 8 + l) * 256 + i * 8 + m)) * 343;
      // n-contiguous stores: lanes n=tid..  -> fully coalesced rows
      dst[tid] = kT[kk][tid] * c;
      if (tid < 343 - 256) dst[tid + 256] = kT[kk][tid + 256] * c;
    }
  }
}

extern "C" void kernel_launch(void* const* d_in, const int* in_sizes, int n_in,
                              void* d_out, int out_size, void* d_ws,
                              size_t ws_size, hipStream_t stream) {
  const float* condition     = (const float*)d_in[0];
  const float* rel_pos_sigma = (const float*)d_in[1];
  const float* cayley_w      = (const float*)d_in[2];
  const float* lin0_W        = (const float*)d_in[3];
  const float* lin0_b        = (const float*)d_in[4];
  const float* act0_a        = (const float*)d_in[5];
  const float* act0_b        = (const float*)d_in[6];
  const float* gps_w         = (const float*)d_in[7];
  const float* lins_W        = (const float*)d_in[8];
  const float* lins_b        = (const float*)d_in[9];
  const float* acts_a        = (const float*)d_in[10];
  const float* acts_b        = (const float*)d_in[11];
  const float* out_W         = (const float*)d_in[12];
  const float* out_b         = (const float*)d_in[13];
  const float* shell_sigma   = (const float*)d_in[14];

  float* ws = (float*)d_ws;
  float* kws = ws + OFF_KWS;
  float* out = (float*)d_out;

  ccs_prep_kernel<<<dim3(640), dim3(256), 0, stream>>>(lin0_W, lins_W, gps_w,
                                                       out_W, ws);
  ccs_net_kernel<<<dim3((NGRID + 1) / 2), dim3(512), 0, stream>>>(
      condition, rel_pos_sigma, lin0_b, act0_a, act0_b, lins_b, acts_a, acts_b,
      out_b, shell_sigma, ws, kws);
  ccs_expand_kernel<<<dim3(1024), dim3(256), 0, stream>>>(cayley_w, kws, out);
}

// Round 8
// 223.373 us; speedup vs baseline: 3.1697x; 3.1697x over previous
//
#include <hip/hip_runtime.h>
#include <math.h>

#define NB 8
#define NGRID 343
#define HID 64
#define NPATH 20

// ---------------- compile-time Clifford tables (Cl(3,0), blade order:
// 1, e1, e2, e3, e12, e13, e23, e123 — matches reference combinations order) ---
struct Tab {
  int prod_idx[8][8];  // blade index of product blade_k * blade_m
  int prod_sgn[8][8];  // sign of that product
  int pid[4][4][4];    // path id for (grade_left, grade_out, grade_right), 20 = dead
  int grade[8];        // grade of blade idx
  int kk_idx[8][8];    // for (l,m): unique k with prod(k,m) = +-l
  int kk_sgn[8][8];    // C[kk, l, m]
};

constexpr Tab make_tab() {
  Tab t{};
  int mask[8]  = {0,1,2,4,3,5,6,7};  // blade idx -> bitmask
  int idxof[8] = {0,1,2,4,3,5,6,7};  // bitmask -> blade idx
  for (int k = 0; k < 8; ++k) {
    int g = 0;
    for (int b = 0; b < 3; ++b) g += (mask[k] >> b) & 1;
    t.grade[k] = g;
  }
  for (int k = 0; k < 8; ++k)
    for (int m = 0; m < 8; ++m) {
      int A = mask[k], B = mask[m];
      t.prod_idx[k][m] = idxof[A ^ B];
      int c = 0;
      for (int i = 0; i < 3; ++i)
        if ((B >> i) & 1)
          for (int j = i + 1; j < 3; ++j)
            if ((A >> j) & 1) c++;
      t.prod_sgn[k][m] = (c & 1) ? -1 : 1;
    }
  int pc = 0;
  for (int a = 0; a < 4; ++a)
    for (int b = 0; b < 4; ++b)
      for (int c = 0; c < 4; ++c) {
        bool ok = false;
        for (int k = 0; k < 8; ++k)
          for (int m = 0; m < 8; ++m)
            if (t.grade[k] == a && t.grade[m] == c &&
                t.grade[t.prod_idx[k][m]] == b)
              ok = true;
        t.pid[a][b][c] = ok ? pc++ : NPATH;
      }
  for (int l = 0; l < 8; ++l)
    for (int m = 0; m < 8; ++m)
      for (int k = 0; k < 8; ++k)
        if (t.prod_idx[k][m] == l) {
          t.kk_idx[l][m] = k;
          t.kk_sgn[l][m] = t.prod_sgn[k][m];
        }
  return t;
}
constexpr Tab TB = make_tab();

// ---------------- workspace layout (floats) ----------------
// lin0_t [4][33][64]          @ 0        (8448)   ([g][ch][hh])
// lins_t [3][4][64][64]       @ 8448     (49152)  ([l][g][i][hh])
// gps_t  [4][64][20][64]      @ 57600    (327680) ([l][i][p][o])
// outW_t [4][64][1024]        @ 385280   (262144) ([g][i][oc])
// k_ws   [1024][343][8]       @ 647424   (2809856)
// JOURNAL (hard-won, do not regress):
//  - Weight loads must be lane-coalesced (4B/lane x 64 = 256B/inst).
//    v3's per-thread float4 from strided bases = 64-line scatter -> 97->160us.
//  - v4/v7: hand-prefetch into register arrays (wn[20]) spills — v7 with
//    full unroll hoisted ALL prefetch loads -> ~1GB scratch traffic, 576us.
//    NEVER register-prefetch here.
//  - v5: LDS staging via __syncthreads() double-buffer -> 105us:
//    __syncthreads drains vmcnt(0); prefetch cannot cross it.
//  - v8: wch[3] overflowed LDS (164960 > 163840). Budget: xb 1056 + x0r 64
//    + F0/F1 8192 + part 32768 leaves ~121KB for weight chunks -> dbuf only.
//  - v9 (this): global_load_lds + per-wave counted vmcnt, wave-private
//    slices, DOUBLE buffer (81920B), issue chunk c+2 after compute(c).
//  - expand is NOT ~100us (r5); total-net ≈ 129us ≈ expand(~25)+prep(~5)
//    + harness/reset overhead.
#define OFF_LIN0T 0
#define OFF_LINST 8448
#define OFF_GPST  57600
#define OFF_OUTWT 385280
#define OFF_KWS   647424

// ---------------- kernel 0: weight transpose ----------------
__global__ void ccs_prep_kernel(const float* __restrict__ lin0_W,
                                const float* __restrict__ lins_W,
                                const float* __restrict__ gps_w,
                                const float* __restrict__ out_W,
                                float* __restrict__ ws) {
  const int TOT = 8448 + 49152 + 327680 + 262144;
  for (int d = blockIdx.x * blockDim.x + threadIdx.x; d < TOT;
       d += gridDim.x * blockDim.x) {
    float v;
    if (d < 8448) {
      int idx = d;
      int hh = idx & 63, ch = (idx >> 6) % 33, g = (idx >> 6) / 33;
      v = lin0_W[(g * 64 + hh) * 33 + ch];
    } else if (d < 8448 + 49152) {
      int idx = d - OFF_LINST;
      int hh = idx & 63, i = (idx >> 6) & 63, g = (idx >> 12) & 3, l = idx >> 14;
      v = lins_W[((l * 4 + g) * 64 + hh) * 64 + i];
    } else if (d < 8448 + 49152 + 327680) {
      int idx = d - OFF_GPST;
      int o = idx & 63, p = (idx >> 6) % 20, i = ((idx >> 6) / 20) & 63,
          l = idx / 81920;
      v = gps_w[((l * 64 + o) * 64 + i) * 20 + p];
    } else {
      int idx = d - OFF_OUTWT;
      int oc = idx & 1023, i = (idx >> 10) & 63, g = idx >> 16;
      v = out_W[(g * 1024 + oc) * 64 + i];
    }
    ws[d] = v;
  }
}

// async global->LDS: 64 lanes x 16B; lds dest = wave-uniform base + lane*16.
__device__ __forceinline__ void glds16(const float* g, float* l) {
  __builtin_amdgcn_global_load_lds(
      (const __attribute__((address_space(1))) unsigned int*)g,
      (__attribute__((address_space(3))) unsigned int*)l, 16, 0, 0);
}

// ---------------- kernel 1: per-grid-point network ----------------
// v9 = v2 (97us verified) with gp weights streamed via global_load_lds:
// chunk c = i in [8c,8c+8), double-buffered 40KB LDS chunks, 2 chunks in
// flight. Wave w stages & reads ONLY rows i=8c+w (its 5 dwordx4 insts
// cover floats [1280w,1280w+1280) of the chunk) -> no cross-wave
// coupling, no barriers in the chunk loop, per-wave s_waitcnt vmcnt only.
__launch_bounds__(512)
__global__ void ccs_net_kernel(const float* __restrict__ condition,
                               const float* __restrict__ rel_pos_sigma,
                               const float* __restrict__ lin0_b,
                               const float* __restrict__ act0_a,
                               const float* __restrict__ act0_b,
                               const float* __restrict__ lins_b,
                               const float* __restrict__ acts_a,
                               const float* __restrict__ acts_b,
                               const float* __restrict__ out_b,
                               const float* __restrict__ shell_sigma,
                               const float* __restrict__ ws,
                               float* __restrict__ kws) {
  const float* lin0t = ws + OFF_LIN0T;
  const float* linst = ws + OFF_LINST;
  const float* gpst  = ws + OFF_GPST;
  const float* outwt = ws + OFF_OUTWT;

  __shared__ float xb[33 * 8];       // condition channels (shared by both pts)
  __shared__ float x0r[2][8];        // per-point geometric row (ch 0)
  __shared__ __align__(16) float F0[2 * 512];
  __shared__ __align__(16) float F1[2 * 512];
  __shared__ float part[2 * 8 * 8 * 64];  // [pt][isub][j][o] stride-1 in o
  __shared__ __align__(16) float wch[2][10240];  // gp weight chunks (80KB)

  const int tid = threadIdx.x;
  const int n0 = blockIdx.x * 2;
  const int n1 = n0 + 1;

  const float sig = rel_pos_sigma[0];

  float qq[2];
  {
    int iz = n0 % 7, iy = (n0 / 7) % 7, ix = n0 / 49;
    float px = (float)ix - 3.f, py = (float)iy - 3.f, pz = (float)iz - 3.f;
    qq[0] = px * px + py * py + pz * pz;
  }
  {
    int nc = (n1 < NGRID) ? n1 : (NGRID - 1);  // clamp: last block's pt1
    int iz = nc % 7, iy = (nc / 7) % 7, ix = nc / 49;
    float px = (float)ix - 3.f, py = (float)iy - 3.f, pz = (float)iz - 3.f;
    qq[1] = px * px + py * py + pz * pz;
  }

  for (int t = tid; t < 264; t += 512) {
    int ch = t >> 3, b = t & 7;
    xb[t] = (ch == 0) ? 0.f : condition[(ch - 1) * 8 + b];
  }
  if (tid < 16) {
    int pt = tid >> 3, b = tid & 7;
    int nc = n0 + pt;
    if (nc >= NGRID) nc = NGRID - 1;
    int iz = nc % 7, iy = (nc / 7) % 7, ix = nc / 49;
    float px = (float)ix - 3.f, py = (float)iy - 3.f, pz = (float)iz - 3.f;
    float q = px * px + py * py + pz * pz;
    float scal = expf(-q / (2.f * sig * sig));
    x0r[pt][b] =
        (b == 0) ? scal : (b == 1) ? px : (b == 2) ? py : (b == 3) ? pz : 0.f;
  }
  __syncthreads();

  const int b8 = tid & 7;
  const int hh = (tid >> 3) & 63;  // 0..63
  const int gb = TB.grade[b8];

  // ---- lin0: x (33 ch) -> F0, both points per thread ----
  {
    const float* wrow = lin0t + gb * 33 * 64 + hh;
    float w0 = wrow[0];
    float a0 = w0 * x0r[0][b8];
    float a1 = w0 * x0r[1][b8];
    if (b8 == 0) {
      float bb = lin0_b[hh];
      a0 += bb;
      a1 += bb;
    }
    #pragma unroll
    for (int ch = 1; ch < 33; ++ch) {
      float w = wrow[ch * 64];
      float xv = xb[ch * 8 + b8];
      a0 = fmaf(w, xv, a0);
      a1 = fmaf(w, xv, a1);
    }
    F0[hh * 8 + b8] = a0;
    F0[512 + hh * 8 + b8] = a1;
  }
  __syncthreads();

  // ---- helpers (src/dst are [2][512] bases; pt stride 512) ----
  auto silu = [&](const float* src, float* dst, const float* aa,
                  const float* bb) {
    int s0 = (gb == 0) ? 0 : (gb == 1) ? 1 : (gb == 2) ? 4 : 7;
    int cnt = (gb == 0 || gb == 3) ? 1 : 3;
    float A = aa[hh * 4 + gb], B = bb[hh * 4 + gb];
    #pragma unroll
    for (int pt = 0; pt < 2; ++pt) {
      float qg = 0.f;
      for (int u = 0; u < cnt; ++u) {
        float v = src[pt * 512 + hh * 8 + s0 + u];
        qg = fmaf(v, v, qg);
      }
      float z = fmaf(A, qg, B);
      float gate = 1.f / (1.f + expf(-z));
      dst[pt * 512 + hh * 8 + b8] = src[pt * 512 + hh * 8 + b8] * gate;
    }
  };

  auto lin = [&](const float* src, float* dst, const float* wt,
                 const float* bias) {
    const float* wrow = wt + gb * 64 * 64 + hh;
    float a0 = 0.f, a1 = 0.f;
    if (b8 == 0) {
      float bb = bias[hh];
      a0 = bb;
      a1 = bb;
    }
    #pragma unroll
    for (int i = 0; i < 64; ++i) {
      float w = wrow[i * 64];
      a0 = fmaf(w, src[i * 8 + b8], a0);
      a1 = fmaf(w, src[512 + i * 8 + b8], a1);
    }
    dst[hh * 8 + b8] = a0;
    dst[512 + hh * 8 + b8] = a1;
  };

  // gp with async-staged weight chunks (wl = global gpst + layer*81920).
  auto gp = [&](const float* src, float* dst, const float* wl) {
    const int o = tid & 63;
    const int w = tid >> 6;        // wave id 0..7
    const int w5 = w * 5;
    const int ln4 = (tid & 63) * 4;  // lane slot (floats): lane*16B
    float fa[8], fb[8];
    #pragma unroll
    for (int j = 0; j < 8; ++j) {
      fa[j] = 0.f;
      fb[j] = 0.f;
    }
    // wave w stages its own rows: insts t=5w..5w+4 cover floats
    // [1280w, 1280w+1280) of the chunk = i-row w, exactly what it reads.
    auto issue = [&](int c) {
      const float* gbch = wl + c * 10240;
      float* lbch = &wch[c & 1][0];
      #pragma unroll
      for (int u = 0; u < 5; ++u) {
        int t = w5 + u;
        glds16(gbch + t * 256 + ln4, lbch + t * 256);
      }
    };
    issue(0);
    issue(1);
    for (int c = 0; c < 8; ++c) {
      if (c < 7) {
        asm volatile("s_waitcnt vmcnt(5)" ::: "memory");  // chunk c landed
      } else {
        asm volatile("s_waitcnt vmcnt(0)" ::: "memory");
      }
      const int i = c * 8 + w;
      const float* wp_l = &wch[c & 1][w * 1280 + o];
      float wp[20];
      #pragma unroll
      for (int p = 0; p < 20; ++p) wp[p] = wp_l[p * 64];  // lanes stride-1
      float4 va0 = *(const float4*)(src + i * 8);
      float4 va1 = *(const float4*)(src + i * 8 + 4);
      float4 vb0 = *(const float4*)(src + 512 + i * 8);
      float4 vb1 = *(const float4*)(src + 512 + i * 8 + 4);
      float xA[8] = {va0.x, va0.y, va0.z, va0.w, va1.x, va1.y, va1.z, va1.w};
      float xB[8] = {vb0.x, vb0.y, vb0.z, vb0.w, vb1.x, vb1.y, vb1.z, vb1.w};
      #pragma unroll
      for (int k = 0; k < 8; ++k) {
        #pragma unroll
        for (int m = 0; m < 8; ++m) {
          const int j = TB.prod_idx[k][m];
          const int p = TB.pid[TB.grade[k]][TB.grade[j]][TB.grade[m]];
          if (TB.prod_sgn[k][m] > 0) {
            fa[j] = fmaf(xA[k] * xA[m], wp[p], fa[j]);
            fb[j] = fmaf(xB[k] * xB[m], wp[p], fb[j]);
          } else {
            fa[j] = fmaf(-xA[k] * xA[m], wp[p], fa[j]);
            fb[j] = fmaf(-xB[k] * xB[m], wp[p], fb[j]);
          }
        }
      }
      // chunk c fully consumed (wp in regs); its buffer (c&1) is free.
      if (c < 6) issue(c + 2);
    }
    // wave w summed i = w, 8+w, ..., 56+w; union over waves = all i.
    // part layout [pt][wave][j][o]: stride-1 in o -> conflict-free
    #pragma unroll
    for (int j = 0; j < 8; ++j) {
      part[w * 512 + j * 64 + o] = fa[j];
      part[4096 + w * 512 + j * 64 + o] = fb[j];
    }
    __syncthreads();
    #pragma unroll
    for (int r = 0; r < 2; ++r) {
      int item = tid + r * 512;  // 1024 items = 2pt x 8j x 64o
      int oo = item & 63;
      int j = (item >> 6) & 7;
      int pt = item >> 9;
      const float* pp = part + pt * 4096 + j * 64 + oo;
      float s = pp[0] + pp[512] + pp[1024] + pp[1536] + pp[2048] + pp[2560] +
                pp[3072] + pp[3584];
      dst[pt * 512 + oo * 8 + j] = s * 0.125f;
    }
    __syncthreads();
  };

  // ---- layer 0 ----
  silu(F0, F1, act0_a, act0_b);
  __syncthreads();
  gp(F1, F0, gpst + 0);  // features now in F0

  // ---- layers 1..3 ----
  float* f = F0;
  float* g_ = F1;
  for (int l = 0; l < 3; ++l) {
    lin(f, g_, linst + l * 16384, lins_b + l * 64);
    __syncthreads();
    silu(g_, f, acts_a + l * 256, acts_b + l * 256);
    __syncthreads();
    gp(f, g_, gpst + (l + 1) * 81920);  // result in g_
    float* t = f; f = g_; g_ = t;       // features in f
  }

  // ---- output linear + shell (both points per thread) ----
  const float FACTOR = 1.0f / sqrtf(343.0f);
  #pragma unroll
  for (int r = 0; r < 2; ++r) {
    int oc = tid + r * 512;
    float acc[2][8];
    #pragma unroll
    for (int pt = 0; pt < 2; ++pt)
      #pragma unroll
      for (int b = 0; b < 8; ++b) acc[pt][b] = 0.f;
    {
      float bb = out_b[oc];
      acc[0][0] = bb;
      acc[1][0] = bb;
    }
    #pragma unroll 4
    for (int i = 0; i < 64; ++i) {
      float w0 = outwt[(0 * 64 + i) * 1024 + oc];
      float w1 = outwt[(1 * 64 + i) * 1024 + oc];
      float w2 = outwt[(2 * 64 + i) * 1024 + oc];
      float w3 = outwt[(3 * 64 + i) * 1024 + oc];
      #pragma unroll
      for (int pt = 0; pt < 2; ++pt) {
        float h[8];
        *(float4*)h = *(const float4*)(f + pt * 512 + i * 8);
        *(float4*)(h + 4) = *(const float4*)(f + pt * 512 + i * 8 + 4);
        acc[pt][0] = fmaf(w0, h[0], acc[pt][0]);
        acc[pt][1] = fmaf(w1, h[1], acc[pt][1]);
        acc[pt][2] = fmaf(w1, h[2], acc[pt][2]);
        acc[pt][3] = fmaf(w1, h[3], acc[pt][3]);
        acc[pt][4] = fmaf(w2, h[4], acc[pt][4]);
        acc[pt][5] = fmaf(w2, h[5], acc[pt][5]);
        acc[pt][6] = fmaf(w2, h[6], acc[pt][6]);
        acc[pt][7] = fmaf(w3, h[7], acc[pt][7]);
      }
    }
    float sh[8];
    *(float4*)sh = *(const float4*)(shell_sigma + oc * 8);
    *(float4*)(sh + 4) = *(const float4*)(shell_sigma + oc * 8 + 4);
    #pragma unroll
    for (int pt = 0; pt < 2; ++pt) {
      int n = n0 + pt;
      if (n < NGRID) {
        float q = qq[pt];
        float out8[8];
        #pragma unroll
        for (int b = 0; b < 8; ++b)
          out8[b] = acc[pt][b] * expf(-q / (sh[b] * sh[b])) * FACTOR;
        float4* dstp = (float4*)(kws + ((size_t)oc * 343 + n) * 8);
        dstp[0] = make_float4(out8[0], out8[1], out8[2], out8[3]);
        dstp[1] = make_float4(out8[4], out8[5], out8[6], out8[7]);
      }
    }
  }
}

// ---------------- kernel 2: Cayley expansion to output ----------------
// One block (256 thr) per oi. kws[oi] staged transposed in LDS
// (kT[b][n], stride-1 reads), output written as n-contiguous coalesced
// rows (64 rows x 343 floats per block).
__launch_bounds__(256)
__global__ void ccs_expand_kernel(const float* __restrict__ cayley_w,
                                  const float* __restrict__ kws,
                                  float* __restrict__ out) {
  const int oi = blockIdx.x;  // o*32 + i, 0..1023
  const int tid = threadIdx.x;
  __shared__ float kT[8][344];  // [blade][n], padded

  // stage kws[oi][n][b] -> kT[b][n] (coalesced float4 reads)
  const float4* src = (const float4*)(kws + (size_t)oi * 343 * 8);
  for (int t = tid; t < 686; t += 256) {  // 686 float4 = 343*8 floats
    float4 v = src[t];
    int n = t >> 1, b = (t & 1) * 4;
    kT[b][n] = v.x;
    kT[b + 1][n] = v.y;
    kT[b + 2][n] = v.z;
    kT[b + 3][n] = v.w;
  }
  float cw[20];
  #pragma unroll
  for (int p = 0; p < 20; ++p) cw[p] = cayley_w[oi * 20 + p];  // broadcast
  __syncthreads();

  const int o = oi >> 5, i = oi & 31;
  #pragma unroll
  for (int l = 0; l < 8; ++l) {
    #pragma unroll
    for (int m = 0; m < 8; ++m) {
      const int kk = TB.kk_idx[l][m];
      const int p = TB.pid[TB.grade[kk]][TB.grade[l]][TB.grade[m]];
      float c = (TB.kk_sgn[l][m] < 0) ? -cw[p] : cw[p];
      float* dst = out + ((size_t)((o * 8 + l) * 256 + i * 8 + m)) * 343;
      // n-contiguous stores: lanes n=tid..  -> fully coalesced rows
      dst[tid] = kT[kk][tid] * c;
      if (tid < 343 - 256) dst[tid + 256] = kT[kk][tid + 256] * c;
    }
  }
}

extern "C" void kernel_launch(void* const* d_in, const int* in_sizes, int n_in,
                              void* d_out, int out_size, void* d_ws,
                              size_t ws_size, hipStream_t stream) {
  const float* condition     = (const float*)d_in[0];
  const float* rel_pos_sigma = (const float*)d_in[1];
  const float* cayley_w      = (const float*)d_in[2];
  const float* lin0_W        = (const float*)d_in[3];
  const float* lin0_b        = (const float*)d_in[4];
  const float* act0_a        = (const float*)d_in[5];
  const float* act0_b        = (const float*)d_in[6];
  const float* gps_w         = (const float*)d_in[7];
  const float* lins_W        = (const float*)d_in[8];
  const float* lins_b        = (const float*)d_in[9];
  const float* acts_a        = (const float*)d_in[10];
  const float* acts_b        = (const float*)d_in[11];
  const float* out_W         = (const float*)d_in[12];
  const float* out_b         = (const float*)d_in[13];
  const float* shell_sigma   = (const float*)d_in[14];

  float* ws = (float*)d_ws;
  float* kws = ws + OFF_KWS;
  float* out = (float*)d_out;

  ccs_prep_kernel<<<dim3(640), dim3(256), 0, stream>>>(lin0_W, lins_W, gps_w,
                                                       out_W, ws);
  ccs_net_kernel<<<dim3((NGRID + 1) / 2), dim3(512), 0, stream>>>(
      condition, rel_pos_sigma, lin0_b, act0_a, act0_b, lins_b, acts_a, acts_b,
      out_b, shell_sigma, ws, kws);
  ccs_expand_kernel<<<dim3(1024), dim3(256), 0, stream>>>(cayley_w, kws, out);
}